// Round 1
// baseline (2562.214 us; speedup 1.0000x reference)
//
#include <hip/hip_runtime.h>
#include <cstddef>

#define NNODES 20000   // B*N
#define TT 16
#define EE 80000
#define BE 320000      // B*E
#define EB 340000      // BE + NNODES (self loops)
#define NPER 5000

__device__ __forceinline__ float sigf(float x) { return 1.0f / (1.0f + __expf(-x)); }
__device__ __forceinline__ float lreluf(float x) { return x > 0.0f ? x : 0.2f * x; }

// ---------------- CSR setup ----------------
__global__ __launch_bounds__(256) void deg_count_k(const int* __restrict__ eidx, int* __restrict__ deg) {
  int e = blockIdx.x * 256 + threadIdx.x;
  if (e >= EB) return;
  int dst;
  if (e < BE) { int r = e % EE; int b = e / EE; dst = eidx[EE + r] + b * NPER; }
  else dst = e - BE;
  atomicAdd(&deg[dst], 1);
}

__global__ __launch_bounds__(1024) void scan_k(const int* __restrict__ deg, int* __restrict__ startp) {
  __shared__ int buf[1024];
  __shared__ int carry_s;
  int tid = threadIdx.x;
  if (tid == 0) carry_s = 0;
  __syncthreads();
  for (int base = 0; base < NNODES; base += 1024) {
    int i = base + tid;
    int v = (i < NNODES) ? deg[i] : 0;
    buf[tid] = v;
    __syncthreads();
    for (int off = 1; off < 1024; off <<= 1) {
      int tv = (tid >= off) ? buf[tid - off] : 0;
      __syncthreads();
      buf[tid] += tv;
      __syncthreads();
    }
    int incl = buf[tid];
    int carry = carry_s;
    if (i < NNODES) startp[i] = carry + incl - v;   // exclusive
    __syncthreads();
    if (tid == 1023) carry_s = carry + incl;
    __syncthreads();
  }
  if (tid == 0) startp[NNODES] = carry_s;
}

__global__ __launch_bounds__(256) void fill_k(const int* __restrict__ eidx, const int* __restrict__ startp,
                                              int* __restrict__ cnt, int* __restrict__ adj) {
  int e = blockIdx.x * 256 + threadIdx.x;
  if (e >= EB) return;
  int src, dst;
  if (e < BE) { int r = e % EE; int b = e / EE; src = eidx[r] + b * NPER; dst = eidx[EE + r] + b * NPER; }
  else { src = e - BE; dst = src; }
  int p = atomicAdd(&cnt[dst], 1);
  adj[startp[dst] + p] = src;
}

// ---------------- generic tiled f32 GEMM: C[M,N] = concat_k(A segs) @ concat_k(W segs)^T ----------------
// A segs: each [M,64] row-major (stride 64). W segs: rows W[n][k_local] at Wp + n*wld.
// Optional bias0+bias1 per column, optional relu.
// Optional fused GAT head-reduction (only for the N=64 xt GEMM): asrc/adst [M,4].
__global__ __launch_bounds__(256) void gemm_k64(
    const float* __restrict__ A0, const float* __restrict__ A1, const float* __restrict__ A2,
    const float* __restrict__ W0, const float* __restrict__ W1, const float* __restrict__ W2,
    int wld, int nseg, int M, int N,
    const float* __restrict__ bias0, const float* __restrict__ bias1,
    int relu, float* __restrict__ C, int cld,
    const float* __restrict__ attS, const float* __restrict__ attD,
    float* __restrict__ asrcOut, float* __restrict__ adstOut)
{
  __shared__ float As[16][132];
  __shared__ float Bs[16][68];
  const int tid = threadIdx.x;
  const int m0 = blockIdx.x * 128;
  const int n0 = blockIdx.y * 64;
  const int tr = tid >> 4;   // 0..15
  const int tc = tid & 15;   // 0..15
  float acc[8][4];
#pragma unroll
  for (int r = 0; r < 8; ++r)
#pragma unroll
    for (int c = 0; c < 4; ++c) acc[r][c] = 0.0f;

  const int lk = (tid & 3) * 4;   // k offset within tile for loads
  const int lm = tid >> 2;        // 0..63

  for (int seg = 0; seg < nseg; ++seg) {
    const float* Ap = (seg == 0) ? A0 : ((seg == 1) ? A1 : A2);
    const float* Wp = (seg == 0) ? W0 : ((seg == 1) ? W1 : W2);
    for (int ko = 0; ko < 64; ko += 16) {
      // A tile 128x16 (stored k-major)
#pragma unroll
      for (int i = 0; i < 2; ++i) {
        int m = lm + i * 64;
        int gm = m0 + m;
        float4 v = make_float4(0.f, 0.f, 0.f, 0.f);
        if (gm < M) v = *reinterpret_cast<const float4*>(Ap + (size_t)gm * 64 + ko + lk);
        As[lk + 0][m] = v.x; As[lk + 1][m] = v.y; As[lk + 2][m] = v.z; As[lk + 3][m] = v.w;
      }
      // B tile 16x64
      {
        int gn = n0 + lm;
        float4 v = make_float4(0.f, 0.f, 0.f, 0.f);
        if (gn < N) v = *reinterpret_cast<const float4*>(Wp + (size_t)gn * wld + ko + lk);
        Bs[lk + 0][lm] = v.x; Bs[lk + 1][lm] = v.y; Bs[lk + 2][lm] = v.z; Bs[lk + 3][lm] = v.w;
      }
      __syncthreads();
#pragma unroll
      for (int k = 0; k < 16; ++k) {
        float4 a0 = *reinterpret_cast<const float4*>(&As[k][tr * 8]);
        float4 a1 = *reinterpret_cast<const float4*>(&As[k][tr * 8 + 4]);
        float4 bb = *reinterpret_cast<const float4*>(&Bs[k][tc * 4]);
        float av[8] = {a0.x, a0.y, a0.z, a0.w, a1.x, a1.y, a1.z, a1.w};
        float bv[4] = {bb.x, bb.y, bb.z, bb.w};
#pragma unroll
        for (int r = 0; r < 8; ++r)
#pragma unroll
          for (int c = 0; c < 4; ++c)
            acc[r][c] = fmaf(av[r], bv[c], acc[r][c]);
      }
      __syncthreads();
    }
  }

  // epilogue
#pragma unroll
  for (int r = 0; r < 8; ++r) {
    int gm = m0 + tr * 8 + r;
    if (gm < M) {
#pragma unroll
      for (int c = 0; c < 4; ++c) {
        int gn = n0 + tc * 4 + c;
        if (gn < N) {
          float v = acc[r][c];
          if (bias0) v += bias0[gn];
          if (bias1) v += bias1[gn];
          if (relu) v = fmaxf(v, 0.0f);
          C[(size_t)gm * cld + gn] = v;
          acc[r][c] = v;
        }
      }
    }
  }

  if (attS != nullptr) {
    // fused per-head attention coefficients (valid for N==64, n0==0)
    int g = tc >> 2;  // head
    float s0 = attS[tc * 4 + 0], s1 = attS[tc * 4 + 1], s2 = attS[tc * 4 + 2], s3 = attS[tc * 4 + 3];
    float d0 = attD[tc * 4 + 0], d1 = attD[tc * 4 + 1], d2 = attD[tc * 4 + 2], d3 = attD[tc * 4 + 3];
#pragma unroll
    for (int r = 0; r < 8; ++r) {
      float ps = acc[r][0] * s0 + acc[r][1] * s1 + acc[r][2] * s2 + acc[r][3] * s3;
      float pd = acc[r][0] * d0 + acc[r][1] * d1 + acc[r][2] * d2 + acc[r][3] * d3;
      ps += __shfl_xor(ps, 1); ps += __shfl_xor(ps, 2);
      pd += __shfl_xor(pd, 1); pd += __shfl_xor(pd, 2);
      int gm = m0 + tr * 8 + r;
      if ((tc & 3) == 0 && gm < M) {
        asrcOut[gm * 4 + g] = ps;
        adstOut[gm * 4 + g] = pd;
      }
    }
  }
}

// ---------------- edge softmax + aggregation: wave per dst node ----------------
__global__ __launch_bounds__(256) void edge_gather_k(
    const int* __restrict__ startp, const int* __restrict__ adj,
    const float* __restrict__ asrc, const float* __restrict__ adst,
    const float* __restrict__ xt, const float* __restrict__ bias,
    float* __restrict__ sp)
{
  int node = blockIdx.x * 4 + (threadIdx.x >> 6);
  if (node >= NNODES) return;
  int lane = threadIdx.x & 63;
  int s0 = startp[node];
  int deg = startp[node + 1] - s0;

  float4 adv = *reinterpret_cast<const float4*>(adst + (size_t)node * 4);
  float ad0 = adv.x, ad1 = adv.y, ad2 = adv.z, ad3 = adv.w;

  float mx0 = -1e30f, mx1 = -1e30f, mx2 = -1e30f, mx3 = -1e30f;
  for (int e = lane; e < deg; e += 64) {
    int src = adj[s0 + e];
    float4 av = *reinterpret_cast<const float4*>(asrc + (size_t)src * 4);
    mx0 = fmaxf(mx0, lreluf(av.x + ad0));
    mx1 = fmaxf(mx1, lreluf(av.y + ad1));
    mx2 = fmaxf(mx2, lreluf(av.z + ad2));
    mx3 = fmaxf(mx3, lreluf(av.w + ad3));
  }
#pragma unroll
  for (int off = 1; off < 64; off <<= 1) {
    mx0 = fmaxf(mx0, __shfl_xor(mx0, off));
    mx1 = fmaxf(mx1, __shfl_xor(mx1, off));
    mx2 = fmaxf(mx2, __shfl_xor(mx2, off));
    mx3 = fmaxf(mx3, __shfl_xor(mx3, off));
  }
  float dn0 = 0.f, dn1 = 0.f, dn2 = 0.f, dn3 = 0.f;
  for (int e = lane; e < deg; e += 64) {
    int src = adj[s0 + e];
    float4 av = *reinterpret_cast<const float4*>(asrc + (size_t)src * 4);
    dn0 += __expf(lreluf(av.x + ad0) - mx0);
    dn1 += __expf(lreluf(av.y + ad1) - mx1);
    dn2 += __expf(lreluf(av.z + ad2) - mx2);
    dn3 += __expf(lreluf(av.w + ad3) - mx3);
  }
#pragma unroll
  for (int off = 1; off < 64; off <<= 1) {
    dn0 += __shfl_xor(dn0, off);
    dn1 += __shfl_xor(dn1, off);
    dn2 += __shfl_xor(dn2, off);
    dn3 += __shfl_xor(dn3, off);
  }
  int h = lane >> 4;
  float mxh = (h == 0) ? mx0 : (h == 1) ? mx1 : (h == 2) ? mx2 : mx3;
  float adh = (h == 0) ? ad0 : (h == 1) ? ad1 : (h == 2) ? ad2 : ad3;
  float dnh = (h == 0) ? dn0 : (h == 1) ? dn1 : (h == 2) ? dn2 : dn3;
  float rdh = 1.0f / (dnh + 1e-16f);

  float accv = 0.0f;
  for (int e = 0; e < deg; ++e) {
    int src = adj[s0 + e];
    float a = lreluf(asrc[src * 4 + h] + adh);
    float alpha = __expf(a - mxh) * rdh;
    accv = fmaf(alpha, xt[(size_t)src * 64 + lane], accv);
  }
  sp[(size_t)node * 64 + lane] = accv + bias[lane];
}

// ---------------- LSTM pointwise + LayerNorm: wave per node ----------------
__global__ __launch_bounds__(256) void lstm_update_k(
    const float* __restrict__ gates, float* __restrict__ cst, float* __restrict__ hst,
    const float* __restrict__ g_ln, const float* __restrict__ b_ln)
{
  int node = blockIdx.x * 4 + (threadIdx.x >> 6);
  if (node >= NNODES) return;
  int lane = threadIdx.x & 63;
  size_t gb = (size_t)node * 256;
  float gi = gates[gb + lane];
  float gf = gates[gb + 64 + lane];
  float gg = gates[gb + 128 + lane];
  float go = gates[gb + 192 + lane];
  float c = cst[(size_t)node * 64 + lane];
  float cn = sigf(gf) * c + sigf(gi) * tanhf(gg);
  float hn = sigf(go) * tanhf(cn);

  float s = hn;
#pragma unroll
  for (int off = 1; off < 64; off <<= 1) s += __shfl_xor(s, off);
  float mu = s * (1.0f / 64.0f);
  float d = hn - mu;
  float v = d * d;
#pragma unroll
  for (int off = 1; off < 64; off <<= 1) v += __shfl_xor(v, off);
  float var = v * (1.0f / 64.0f);
  float hl = d * rsqrtf(var + 1e-5f) * g_ln[lane] + b_ln[lane];
  hst[(size_t)node * 64 + lane] = hl;
  cst[(size_t)node * 64 + lane] = cn;
}

// ---------------- mix finalize: logits -> softmax(3) -> blended output ----------------
__global__ __launch_bounds__(256) void mix_final_k(
    const float* __restrict__ hidden, const float* __restrict__ w2, const float* __restrict__ b2,
    const float* __restrict__ hf, const float* __restrict__ hm, const float* __restrict__ hs,
    float* __restrict__ out, int t)
{
  int node = blockIdx.x * 4 + (threadIdx.x >> 6);
  if (node >= NNODES) return;
  int lane = threadIdx.x & 63;
  size_t hb = (size_t)node * 96;
  float h0 = hidden[hb + lane];
  int j2 = 64 + (lane & 31);
  float h1 = hidden[hb + j2];
  if (lane >= 32) h1 = 0.0f;

  float p0 = w2[lane] * h0 + w2[j2] * h1;
  float p1 = w2[96 + lane] * h0 + w2[96 + j2] * h1;
  float p2 = w2[192 + lane] * h0 + w2[192 + j2] * h1;
#pragma unroll
  for (int off = 1; off < 64; off <<= 1) {
    p0 += __shfl_xor(p0, off);
    p1 += __shfl_xor(p1, off);
    p2 += __shfl_xor(p2, off);
  }
  float l0 = p0 + b2[0], l1 = p1 + b2[1], l2 = p2 + b2[2];
  float m = fmaxf(l0, fmaxf(l1, l2));
  float e0 = __expf(l0 - m), e1 = __expf(l1 - m), e2 = __expf(l2 - m);
  float rs = 1.0f / (e0 + e1 + e2);
  float w0 = e0 * rs, w1v = e1 * rs, w2v = e2 * rs;

  size_t nb = (size_t)node * 64 + lane;
  float o = w0 * hf[nb] + w1v * hm[nb] + w2v * hs[nb];
  out[((size_t)node * TT + t) * 64 + lane] = o;
}

// ---------------- host side ----------------
static inline void run_cell(hipStream_t stream, int c,
    const float* xtp, float* hstate, float* cstate,
    const float* lin_w, const float* att_src, const float* att_dst, const float* gat_bias,
    const float* w_ih, const float* w_hh, const float* b_ih, const float* b_hh,
    const float* ln_g, const float* ln_b,
    float* xt, float* sp, float* gates, float* asrc, float* adst,
    const int* startp, const int* adj)
{
  gemm_k64<<<dim3(157, 1), 256, 0, stream>>>(
      xtp, nullptr, nullptr, lin_w + c * 4096, nullptr, nullptr, 64, 1, NNODES, 64,
      nullptr, nullptr, 0, xt, 64, att_src + c * 64, att_dst + c * 64, asrc, adst);
  edge_gather_k<<<5000, 256, 0, stream>>>(startp, adj, asrc, adst, xt, gat_bias + c * 64, sp);
  gemm_k64<<<dim3(157, 4), 256, 0, stream>>>(
      sp, hstate, nullptr, w_ih + c * 16384, w_hh + c * 16384, nullptr, 64, 2, NNODES, 256,
      b_ih + c * 256, b_hh + c * 256, 0, gates, 256, nullptr, nullptr, nullptr, nullptr);
  lstm_update_k<<<5000, 256, 0, stream>>>(gates, cstate, hstate, ln_g + c * 64, ln_b + c * 64);
}

extern "C" void kernel_launch(void* const* d_in, const int* in_sizes, int n_in,
                              void* d_out, int out_size, void* d_ws, size_t ws_size,
                              hipStream_t stream) {
  const float* x_seq   = (const float*)d_in[0];
  const float* lin_w   = (const float*)d_in[1];
  const float* att_src = (const float*)d_in[2];
  const float* att_dst = (const float*)d_in[3];
  const float* gat_bias= (const float*)d_in[4];
  const float* w_ih    = (const float*)d_in[5];
  const float* w_hh    = (const float*)d_in[6];
  const float* b_ih    = (const float*)d_in[7];
  const float* b_hh    = (const float*)d_in[8];
  const float* ln_g    = (const float*)d_in[9];
  const float* ln_b    = (const float*)d_in[10];
  const float* w1      = (const float*)d_in[11];
  const float* b1      = (const float*)d_in[12];
  const float* w2      = (const float*)d_in[13];
  const float* b2      = (const float*)d_in[14];
  const int*   eidx    = (const int*)d_in[15];
  float* out = (float*)d_out;

  float* fbase = (float*)d_ws;
  float* xt     = fbase;                  // 1,280,000
  float* sp     = xt + 1280000;           // 1,280,000
  float* gates  = sp + 1280000;           // 5,120,000
  float* hidden = gates + 5120000;        // 1,920,000
  float* asrc   = hidden + 1920000;       // 80,000
  float* adst   = asrc + 80000;           // 80,000
  float* hf = adst + 80000;
  float* cf = hf + 1280000;
  float* hm = cf + 1280000;
  float* cm = hm + 1280000;
  float* hs = cm + 1280000;
  float* cs = hs + 1280000;
  int* deg    = (int*)(cs + 1280000);     // 20,000
  int* cnt    = deg + 20000;              // 20,000
  int* startp = cnt + 20000;              // 20,001
  int* adj    = startp + 20001;           // 340,000

  // zero recurrent states + CSR counters
  hipMemsetAsync(hf, 0, (size_t)6 * 1280000 * sizeof(float), stream);
  hipMemsetAsync(deg, 0, (size_t)40000 * sizeof(int), stream);

  deg_count_k<<<(EB + 255) / 256, 256, 0, stream>>>(eidx, deg);
  scan_k<<<1, 1024, 0, stream>>>(deg, startp);
  fill_k<<<(EB + 255) / 256, 256, 0, stream>>>(eidx, startp, cnt, adj);

  for (int t = 0; t < TT; ++t) {
    const float* xtp = x_seq + (size_t)t * NNODES * 64;
    run_cell(stream, 0, xtp, hf, cf, lin_w, att_src, att_dst, gat_bias,
             w_ih, w_hh, b_ih, b_hh, ln_g, ln_b, xt, sp, gates, asrc, adst, startp, adj);
    if (t % 15 == 0)
      run_cell(stream, 1, xtp, hm, cm, lin_w, att_src, att_dst, gat_bias,
               w_ih, w_hh, b_ih, b_hh, ln_g, ln_b, xt, sp, gates, asrc, adst, startp, adj);
    if (t == 0)
      run_cell(stream, 2, xtp, hs, cs, lin_w, att_src, att_dst, gat_bias,
               w_ih, w_hh, b_ih, b_hh, ln_g, ln_b, xt, sp, gates, asrc, adst, startp, adj);

    gemm_k64<<<dim3(157, 2), 256, 0, stream>>>(
        hf, hm, hs, w1, w1 + 64, w1 + 128, 192, 3, NNODES, 96,
        b1, nullptr, 1, hidden, 96, nullptr, nullptr, nullptr, nullptr);
    mix_final_k<<<5000, 256, 0, stream>>>(hidden, w2, b2, hf, hm, hs, out, t);
  }
}

// Round 3
// 2254.235 us; speedup vs baseline: 1.1366x; 1.1366x over previous
//
#include <hip/hip_runtime.h>
#include <cstddef>

#define M_NODES 20000   // B*N
#define TT 16
#define EE 80000
#define BE 320000       // B*E
#define EB 340000       // BE + self loops
#define NPER 5000

typedef __attribute__((ext_vector_type(8))) short bf16x8;
typedef __attribute__((ext_vector_type(4))) float f32x4;

__device__ __forceinline__ float sigf(float x) { return 1.0f / (1.0f + __expf(-x)); }
__device__ __forceinline__ float lreluf(float x) { return x > 0.0f ? x : 0.2f * x; }

__device__ __forceinline__ unsigned short f2bf(float x) {
  union { float f; unsigned u; } v; v.f = x;
  unsigned r = v.u + 0x7FFF + ((v.u >> 16) & 1);   // RNE
  return (unsigned short)(r >> 16);
}
__device__ __forceinline__ float bf2f(unsigned short u) {
  union { unsigned u; float f; } v; v.u = ((unsigned)u) << 16; return v.f;
}
__device__ __forceinline__ f32x4 mfma16(bf16x8 a, bf16x8 b, f32x4 c) {
  return __builtin_amdgcn_mfma_f32_16x16x32_bf16(a, b, c, 0, 0, 0);
}

// ---------------- CSR setup ----------------
__global__ __launch_bounds__(256) void deg_count_k(const int* __restrict__ eidx, int* __restrict__ deg) {
  int e = blockIdx.x * 256 + threadIdx.x;
  if (e >= EB) return;
  int dst;
  if (e < BE) { int r = e % EE; int b = e / EE; dst = eidx[EE + r] + b * NPER; }
  else dst = e - BE;
  atomicAdd(&deg[dst], 1);
}

__global__ __launch_bounds__(1024) void scan_k(const int* __restrict__ deg, int* __restrict__ startp) {
  __shared__ int buf[1024];
  __shared__ int carry_s;
  int tid = threadIdx.x;
  if (tid == 0) carry_s = 0;
  __syncthreads();
  for (int base = 0; base < M_NODES; base += 1024) {
    int i = base + tid;
    int v = (i < M_NODES) ? deg[i] : 0;
    buf[tid] = v;
    __syncthreads();
    for (int off = 1; off < 1024; off <<= 1) {
      int tv = (tid >= off) ? buf[tid - off] : 0;
      __syncthreads();
      buf[tid] += tv;
      __syncthreads();
    }
    int incl = buf[tid];
    int carry = carry_s;
    if (i < M_NODES) startp[i] = carry + incl - v;   // exclusive
    __syncthreads();
    if (tid == 1023) carry_s = carry + incl;
    __syncthreads();
  }
  if (tid == 0) startp[M_NODES] = carry_s;
}

__global__ __launch_bounds__(256) void fill_k(const int* __restrict__ eidx, const int* __restrict__ startp,
                                              int* __restrict__ cnt, int* __restrict__ adj) {
  int e = blockIdx.x * 256 + threadIdx.x;
  if (e >= EB) return;
  int src, dst;
  if (e < BE) { int r = e % EE; int b = e / EE; src = eidx[r] + b * NPER; dst = eidx[EE + r] + b * NPER; }
  else { src = e - BE; dst = src; }
  int p = atomicAdd(&cnt[dst], 1);
  adj[startp[dst] + p] = src;
}

// ---------------- weight conversion f32 -> split bf16 (hi, lo) ----------------
__global__ __launch_bounds__(256) void convert_k(
    const float* __restrict__ lin_w, const float* __restrict__ w_ih, const float* __restrict__ w_hh,
    const float* __restrict__ w1, const float* __restrict__ b_ih, const float* __restrict__ b_hh,
    unsigned short* __restrict__ linH, unsigned short* __restrict__ linL,
    unsigned short* __restrict__ wihH, unsigned short* __restrict__ wihL,
    unsigned short* __restrict__ whhH, unsigned short* __restrict__ whhL,
    unsigned short* __restrict__ w1H, unsigned short* __restrict__ w1L,
    float* __restrict__ bsum)
{
  int i = blockIdx.x * 256 + threadIdx.x;
  if (i < 12288) { float w = lin_w[i]; unsigned short h = f2bf(w); linH[i] = h; linL[i] = f2bf(w - bf2f(h)); }
  if (i < 49152) {
    float w = w_ih[i]; unsigned short h = f2bf(w); wihH[i] = h; wihL[i] = f2bf(w - bf2f(h));
    float v = w_hh[i]; unsigned short g = f2bf(v); whhH[i] = g; whhL[i] = f2bf(v - bf2f(g));
  }
  if (i < 18432) { float w = w1[i]; unsigned short h = f2bf(w); w1H[i] = h; w1L[i] = f2bf(w - bf2f(h)); }
  if (i < 768) bsum[i] = b_ih[i] + b_hh[i];
}

// ---------------- xt GEMM (split MFMA) + fused GAT attention coefficients ----------------
__global__ __launch_bounds__(256) void xt_gemm_k(
    const float* __restrict__ A, const unsigned short* __restrict__ WH, const unsigned short* __restrict__ WL,
    const float* __restrict__ attS, const float* __restrict__ attD,
    float* __restrict__ xt, float* __restrict__ asrc, float* __restrict__ adst)
{
  const int lane = threadIdx.x & 63, wv = threadIdx.x >> 6;
  const int l15 = lane & 15, lg = lane >> 4;
  const int m0 = (blockIdx.x * 4 + wv) * 16;
  int gm = m0 + l15; if (gm >= M_NODES) gm = M_NODES - 1;
  const float* arow = A + (size_t)gm * 64;
  bf16x8 aH[2], aL[2];
#pragma unroll
  for (int ch = 0; ch < 2; ++ch) {
    float4 u0 = *reinterpret_cast<const float4*>(arow + ch * 32 + lg * 8);
    float4 u1 = *reinterpret_cast<const float4*>(arow + ch * 32 + lg * 8 + 4);
    float v[8] = {u0.x, u0.y, u0.z, u0.w, u1.x, u1.y, u1.z, u1.w};
    bf16x8 th, tl;
#pragma unroll
    for (int i = 0; i < 8; ++i) {
      unsigned short hi = f2bf(v[i]);
      th[i] = (short)hi;
      tl[i] = (short)f2bf(v[i] - bf2f(hi));
    }
    aH[ch] = th; aL[ch] = tl;
  }
  f32x4 acc[4];
#pragma unroll
  for (int nf = 0; nf < 4; ++nf) acc[nf] = (f32x4){0.f, 0.f, 0.f, 0.f};
#pragma unroll
  for (int nf = 0; nf < 4; ++nf) {
#pragma unroll
    for (int ch = 0; ch < 2; ++ch) {
      size_t wo = (size_t)(nf * 16 + l15) * 64 + ch * 32 + lg * 8;
      bf16x8 bH = *reinterpret_cast<const bf16x8*>(WH + wo);
      bf16x8 bL = *reinterpret_cast<const bf16x8*>(WL + wo);
      acc[nf] = mfma16(aH[ch], bH, acc[nf]);
      acc[nf] = mfma16(aH[ch], bL, acc[nf]);
      acc[nf] = mfma16(aL[ch], bH, acc[nf]);
    }
  }
#pragma unroll
  for (int nf = 0; nf < 4; ++nf) {
    float sv = attS[nf * 16 + l15], dv = attD[nf * 16 + l15];
#pragma unroll
    for (int r = 0; r < 4; ++r) {
      int row = m0 + lg * 4 + r;
      float v = acc[nf][r];
      float ps = v * sv, pd = v * dv;
#pragma unroll
      for (int off = 1; off < 16; off <<= 1) { ps += __shfl_xor(ps, off); pd += __shfl_xor(pd, off); }
      if (row < M_NODES) {
        xt[(size_t)row * 64 + nf * 16 + l15] = v;
        if (l15 == 0) { asrc[row * 4 + nf] = ps; adst[row * 4 + nf] = pd; }
      }
    }
  }
}

// ---------------- edge softmax + aggregation: wave per dst node ----------------
__global__ __launch_bounds__(256) void gather_k(
    const int* __restrict__ startp, const int* __restrict__ adj,
    const float* __restrict__ asrc, const float* __restrict__ adst,
    const float* __restrict__ xt, const float* __restrict__ bias,
    unsigned short* __restrict__ spH, unsigned short* __restrict__ spL)
{
  int node = blockIdx.x * 4 + (threadIdx.x >> 6);
  if (node >= M_NODES) return;
  int lane = threadIdx.x & 63;
  int s0 = startp[node];
  int deg = startp[node + 1] - s0;

  float4 adv = *reinterpret_cast<const float4*>(adst + (size_t)node * 4);
  float ad0 = adv.x, ad1 = adv.y, ad2 = adv.z, ad3 = adv.w;

  float mx0 = -1e30f, mx1 = -1e30f, mx2 = -1e30f, mx3 = -1e30f;
  for (int e = lane; e < deg; e += 64) {
    int src = adj[s0 + e];
    float4 av = *reinterpret_cast<const float4*>(asrc + (size_t)src * 4);
    mx0 = fmaxf(mx0, lreluf(av.x + ad0));
    mx1 = fmaxf(mx1, lreluf(av.y + ad1));
    mx2 = fmaxf(mx2, lreluf(av.z + ad2));
    mx3 = fmaxf(mx3, lreluf(av.w + ad3));
  }
#pragma unroll
  for (int off = 1; off < 64; off <<= 1) {
    mx0 = fmaxf(mx0, __shfl_xor(mx0, off));
    mx1 = fmaxf(mx1, __shfl_xor(mx1, off));
    mx2 = fmaxf(mx2, __shfl_xor(mx2, off));
    mx3 = fmaxf(mx3, __shfl_xor(mx3, off));
  }
  float dn0 = 0.f, dn1 = 0.f, dn2 = 0.f, dn3 = 0.f;
  for (int e = lane; e < deg; e += 64) {
    int src = adj[s0 + e];
    float4 av = *reinterpret_cast<const float4*>(asrc + (size_t)src * 4);
    dn0 += __expf(lreluf(av.x + ad0) - mx0);
    dn1 += __expf(lreluf(av.y + ad1) - mx1);
    dn2 += __expf(lreluf(av.z + ad2) - mx2);
    dn3 += __expf(lreluf(av.w + ad3) - mx3);
  }
#pragma unroll
  for (int off = 1; off < 64; off <<= 1) {
    dn0 += __shfl_xor(dn0, off);
    dn1 += __shfl_xor(dn1, off);
    dn2 += __shfl_xor(dn2, off);
    dn3 += __shfl_xor(dn3, off);
  }
  int h = lane >> 4;
  float mxh = (h == 0) ? mx0 : (h == 1) ? mx1 : (h == 2) ? mx2 : mx3;
  float adh = (h == 0) ? ad0 : (h == 1) ? ad1 : (h == 2) ? ad2 : ad3;
  float dnh = (h == 0) ? dn0 : (h == 1) ? dn1 : (h == 2) ? dn2 : dn3;
  float rdh = 1.0f / (dnh + 1e-16f);

  float accv = 0.0f;
  for (int e = 0; e < deg; ++e) {
    int src = adj[s0 + e];
    float a = lreluf(asrc[src * 4 + h] + adh);
    float alpha = __expf(a - mxh) * rdh;
    accv = fmaf(alpha, xt[(size_t)src * 64 + lane], accv);
  }
  float v = accv + bias[lane];
  unsigned short hi = f2bf(v);
  spH[(size_t)node * 64 + lane] = hi;
  spL[(size_t)node * 64 + lane] = f2bf(v - bf2f(hi));
}

// ---------------- gates GEMM (split MFMA) + fused LSTM pointwise + LayerNorm ----------------
// In-place h update: each wave's 16-row block is read (A frags) fully before epilogue stores.
__global__ __launch_bounds__(256) void gates_lstm_k(
    const unsigned short* __restrict__ spH, const unsigned short* __restrict__ spL,
    unsigned short* __restrict__ hH, unsigned short* __restrict__ hL,
    const unsigned short* __restrict__ WihH, const unsigned short* __restrict__ WihL,
    const unsigned short* __restrict__ WhhH, const unsigned short* __restrict__ WhhL,
    const float* __restrict__ bsum, float* __restrict__ cst,
    const float* __restrict__ g_ln, const float* __restrict__ b_ln)
{
  const int lane = threadIdx.x & 63, wv = threadIdx.x >> 6;
  const int l15 = lane & 15, lg = lane >> 4;
  const int m0 = (blockIdx.x * 4 + wv) * 16;
  int gm = m0 + l15; if (gm >= M_NODES) gm = M_NODES - 1;
  bf16x8 sHa[2], sLa[2], hHa[2], hLa[2];
#pragma unroll
  for (int ch = 0; ch < 2; ++ch) {
    size_t off = (size_t)gm * 64 + ch * 32 + lg * 8;
    sHa[ch] = *reinterpret_cast<const bf16x8*>(spH + off);
    sLa[ch] = *reinterpret_cast<const bf16x8*>(spL + off);
    hHa[ch] = *reinterpret_cast<const bf16x8*>(hH + off);
    hLa[ch] = *reinterpret_cast<const bf16x8*>(hL + off);
  }
  f32x4 acc[16];
#pragma unroll
  for (int nf = 0; nf < 16; ++nf) acc[nf] = (f32x4){0.f, 0.f, 0.f, 0.f};
#pragma unroll
  for (int nf = 0; nf < 16; ++nf) {
#pragma unroll
    for (int ch = 0; ch < 2; ++ch) {
      size_t wo = (size_t)(nf * 16 + l15) * 64 + ch * 32 + lg * 8;
      bf16x8 bH = *reinterpret_cast<const bf16x8*>(WihH + wo);
      bf16x8 bL = *reinterpret_cast<const bf16x8*>(WihL + wo);
      acc[nf] = mfma16(sHa[ch], bH, acc[nf]);
      acc[nf] = mfma16(sHa[ch], bL, acc[nf]);
      acc[nf] = mfma16(sLa[ch], bH, acc[nf]);
      bf16x8 cH = *reinterpret_cast<const bf16x8*>(WhhH + wo);
      bf16x8 cL = *reinterpret_cast<const bf16x8*>(WhhL + wo);
      acc[nf] = mfma16(hHa[ch], cH, acc[nf]);
      acc[nf] = mfma16(hHa[ch], cL, acc[nf]);
      acc[nf] = mfma16(hLa[ch], cH, acc[nf]);
    }
  }
  float hn[4][4], cn[4][4];
#pragma unroll
  for (int cq = 0; cq < 4; ++cq) {
    int col = cq * 16 + l15;
    float bi = bsum[col], bff = bsum[64 + col], bg = bsum[128 + col], bo = bsum[192 + col];
#pragma unroll
    for (int r = 0; r < 4; ++r) {
      int row = m0 + lg * 4 + r;
      int crow = (row < M_NODES) ? row : (M_NODES - 1);
      float gi = acc[cq][r] + bi;
      float gf = acc[cq + 4][r] + bff;
      float gg = acc[cq + 8][r] + bg;
      float go = acc[cq + 12][r] + bo;
      float cold = cst[(size_t)crow * 64 + col];
      float cv = sigf(gf) * cold + sigf(gi) * tanhf(gg);
      float hv = sigf(go) * tanhf(cv);
      cn[cq][r] = cv; hn[cq][r] = hv;
    }
  }
#pragma unroll
  for (int r = 0; r < 4; ++r) {
    float s = hn[0][r] + hn[1][r] + hn[2][r] + hn[3][r];
#pragma unroll
    for (int off = 1; off < 16; off <<= 1) s += __shfl_xor(s, off);
    float mu = s * (1.0f / 64.0f);
    float vv = 0.f;
#pragma unroll
    for (int cq = 0; cq < 4; ++cq) { float d = hn[cq][r] - mu; vv += d * d; }
#pragma unroll
    for (int off = 1; off < 16; off <<= 1) vv += __shfl_xor(vv, off);
    float rstd = rsqrtf(vv * (1.0f / 64.0f) + 1e-5f);
    int row = m0 + lg * 4 + r;
    if (row < M_NODES) {
#pragma unroll
      for (int cq = 0; cq < 4; ++cq) {
        int col = cq * 16 + l15;
        float hl = (hn[cq][r] - mu) * rstd * g_ln[col] + b_ln[col];
        unsigned short hi = f2bf(hl);
        hH[(size_t)row * 64 + col] = hi;
        hL[(size_t)row * 64 + col] = f2bf(hl - bf2f(hi));
        cst[(size_t)row * 64 + col] = cn[cq][r];
      }
    }
  }
}

// ---------------- mix GEMM (split MFMA) + fused logits/softmax/blend ----------------
__global__ __launch_bounds__(256) void mix_k(
    const unsigned short* __restrict__ hHf, const unsigned short* __restrict__ hLf,
    const unsigned short* __restrict__ hHm, const unsigned short* __restrict__ hLm,
    const unsigned short* __restrict__ hHs, const unsigned short* __restrict__ hLs,
    const unsigned short* __restrict__ W1H, const unsigned short* __restrict__ W1L,
    const float* __restrict__ b1, const float* __restrict__ w2, const float* __restrict__ b2,
    float* __restrict__ out, int t)
{
  const int lane = threadIdx.x & 63, wv = threadIdx.x >> 6;
  const int l15 = lane & 15, lg = lane >> 4;
  const int m0 = (blockIdx.x * 4 + wv) * 16;
  int gm = m0 + l15; if (gm >= M_NODES) gm = M_NODES - 1;
  bf16x8 aH[3][2], aL[3][2];
#pragma unroll
  for (int ch = 0; ch < 2; ++ch) {
    size_t off = (size_t)gm * 64 + ch * 32 + lg * 8;
    aH[0][ch] = *reinterpret_cast<const bf16x8*>(hHf + off);
    aL[0][ch] = *reinterpret_cast<const bf16x8*>(hLf + off);
    aH[1][ch] = *reinterpret_cast<const bf16x8*>(hHm + off);
    aL[1][ch] = *reinterpret_cast<const bf16x8*>(hLm + off);
    aH[2][ch] = *reinterpret_cast<const bf16x8*>(hHs + off);
    aL[2][ch] = *reinterpret_cast<const bf16x8*>(hLs + off);
  }
  f32x4 acc[6];
#pragma unroll
  for (int nf = 0; nf < 6; ++nf) acc[nf] = (f32x4){0.f, 0.f, 0.f, 0.f};
#pragma unroll
  for (int nf = 0; nf < 6; ++nf) {
#pragma unroll
    for (int s = 0; s < 3; ++s) {
#pragma unroll
      for (int ch = 0; ch < 2; ++ch) {
        size_t wo = (size_t)(nf * 16 + l15) * 192 + s * 64 + ch * 32 + lg * 8;
        bf16x8 bH = *reinterpret_cast<const bf16x8*>(W1H + wo);
        bf16x8 bL = *reinterpret_cast<const bf16x8*>(W1L + wo);
        acc[nf] = mfma16(aH[s][ch], bH, acc[nf]);
        acc[nf] = mfma16(aH[s][ch], bL, acc[nf]);
        acc[nf] = mfma16(aL[s][ch], bH, acc[nf]);
      }
    }
  }
#pragma unroll
  for (int r = 0; r < 4; ++r) {
    float p0 = 0.f, p1 = 0.f, p2 = 0.f;
#pragma unroll
    for (int nf = 0; nf < 6; ++nf) {
      int n = nf * 16 + l15;
      float hdv = fmaxf(acc[nf][r] + b1[n], 0.f);
      p0 = fmaf(hdv, w2[n], p0);
      p1 = fmaf(hdv, w2[96 + n], p1);
      p2 = fmaf(hdv, w2[192 + n], p2);
    }
#pragma unroll
    for (int off = 1; off < 16; off <<= 1) {
      p0 += __shfl_xor(p0, off); p1 += __shfl_xor(p1, off); p2 += __shfl_xor(p2, off);
    }
    float q0 = p0 + b2[0], q1 = p1 + b2[1], q2 = p2 + b2[2];
    float mx = fmaxf(q0, fmaxf(q1, q2));
    float e0 = __expf(q0 - mx), e1 = __expf(q1 - mx), e2 = __expf(q2 - mx);
    float rs = 1.0f / (e0 + e1 + e2);
    float w0 = e0 * rs, w1v = e1 * rs, w2v = e2 * rs;
    int row = m0 + lg * 4 + r;
    if (row < M_NODES) {
      size_t ob = ((size_t)row * TT + t) * 64;
      size_t hb = (size_t)row * 64;
#pragma unroll
      for (int q = 0; q < 4; ++q) {
        int col = l15 + 16 * q;
        float vf = bf2f(hHf[hb + col]) + bf2f(hLf[hb + col]);
        float vm = bf2f(hHm[hb + col]) + bf2f(hLm[hb + col]);
        float vs = bf2f(hHs[hb + col]) + bf2f(hLs[hb + col]);
        out[ob + col] = w0 * vf + w1v * vm + w2v * vs;
      }
    }
  }
}

// ---------------- host side ----------------
extern "C" void kernel_launch(void* const* d_in, const int* in_sizes, int n_in,
                              void* d_out, int out_size, void* d_ws, size_t ws_size,
                              hipStream_t stream) {
  const float* x_seq    = (const float*)d_in[0];
  const float* lin_w    = (const float*)d_in[1];
  const float* att_src  = (const float*)d_in[2];
  const float* att_dst  = (const float*)d_in[3];
  const float* gat_bias = (const float*)d_in[4];
  const float* w_ih     = (const float*)d_in[5];
  const float* w_hh     = (const float*)d_in[6];
  const float* b_ih     = (const float*)d_in[7];
  const float* b_hh     = (const float*)d_in[8];
  const float* ln_g     = (const float*)d_in[9];
  const float* ln_b     = (const float*)d_in[10];
  const float* w1       = (const float*)d_in[11];
  const float* b1       = (const float*)d_in[12];
  const float* w2       = (const float*)d_in[13];
  const float* b2       = (const float*)d_in[14];
  const int*   eidx     = (const int*)d_in[15];
  float* out = (float*)d_out;

  char* base = (char*)d_ws;
  float* c_st = (float*)base;                                   // 3,840,000 f32
  unsigned short* hbuf = (unsigned short*)(c_st + 3840000);     // 6 planes x 1,280,000 u16
  int* deg = (int*)(hbuf + 7680000);                            // 20,000
  int* cnt = deg + 20000;                                       // 20,000
  int* startp = cnt + 20000;                                    // 20,001 (pad to 20,008)
  int* adj = startp + 20008;                                    // 340,000
  float* asrc = (float*)(adj + 340000);                         // 80,000
  float* adst = asrc + 80000;                                   // 80,000
  float* bsum = adst + 80000;                                   // 768
  float* xt = bsum + 768;                                       // 1,280,000 f32
  unsigned short* spH = (unsigned short*)(xt + 1280000);        // 1,280,000
  unsigned short* spL = spH + 1280000;                          // 1,280,000
  unsigned short* linH = spL + 1280000;                         // 12,288
  unsigned short* linL = linH + 12288;
  unsigned short* wihH = linL + 12288;                          // 49,152
  unsigned short* wihL = wihH + 49152;
  unsigned short* whhH = wihL + 49152;
  unsigned short* whhL = whhH + 49152;
  unsigned short* w1H = whhL + 49152;                           // 18,432
  unsigned short* w1L = w1H + 18432;

  unsigned short* hHf = hbuf;
  unsigned short* hLf = hbuf + 1280000;
  unsigned short* hHm = hbuf + 2 * 1280000;
  unsigned short* hLm = hbuf + 3 * 1280000;
  unsigned short* hHs = hbuf + 4 * 1280000;
  unsigned short* hLs = hbuf + 5 * 1280000;

  // zero: c (15.36MB) + h planes (15.36MB) + deg/cnt (160KB) — contiguous
  hipMemsetAsync(base, 0, (size_t)3840000 * 4 + (size_t)7680000 * 2 + (size_t)40000 * 4, stream);

  convert_k<<<192, 256, 0, stream>>>(lin_w, w_ih, w_hh, w1, b_ih, b_hh,
                                     linH, linL, wihH, wihL, whhH, whhL, w1H, w1L, bsum);
  deg_count_k<<<(EB + 255) / 256, 256, 0, stream>>>(eidx, deg);
  scan_k<<<1, 1024, 0, stream>>>(deg, startp);
  fill_k<<<(EB + 255) / 256, 256, 0, stream>>>(eidx, startp, cnt, adj);

  for (int t = 0; t < TT; ++t) {
    const float* xtp = x_seq + (size_t)t * 1280000;
    // fast cell
    xt_gemm_k<<<313, 256, 0, stream>>>(xtp, linH, linL, att_src, att_dst, xt, asrc, adst);
    gather_k<<<5000, 256, 0, stream>>>(startp, adj, asrc, adst, xt, gat_bias, spH, spL);
    gates_lstm_k<<<313, 256, 0, stream>>>(spH, spL, hHf, hLf, wihH, wihL, whhH, whhL,
                                          bsum, c_st, ln_g, ln_b);
    if (t % 15 == 0) {
      xt_gemm_k<<<313, 256, 0, stream>>>(xtp, linH + 4096, linL + 4096, att_src + 64, att_dst + 64,
                                         xt, asrc, adst);
      gather_k<<<5000, 256, 0, stream>>>(startp, adj, asrc, adst, xt, gat_bias + 64, spH, spL);
      gates_lstm_k<<<313, 256, 0, stream>>>(spH, spL, hHm, hLm, wihH + 16384, wihL + 16384,
                                            whhH + 16384, whhL + 16384, bsum + 256,
                                            c_st + 1280000, ln_g + 64, ln_b + 64);
    }
    if (t == 0) {
      xt_gemm_k<<<313, 256, 0, stream>>>(xtp, linH + 8192, linL + 8192, att_src + 128, att_dst + 128,
                                         xt, asrc, adst);
      gather_k<<<5000, 256, 0, stream>>>(startp, adj, asrc, adst, xt, gat_bias + 128, spH, spL);
      gates_lstm_k<<<313, 256, 0, stream>>>(spH, spL, hHs, hLs, wihH + 32768, wihL + 32768,
                                            whhH + 32768, whhL + 32768, bsum + 512,
                                            c_st + 2560000, ln_g + 128, ln_b + 128);
    }
    mix_k<<<313, 256, 0, stream>>>(hHf, hLf, hHm, hLm, hHs, hLs, w1H, w1L, b1, w2, b2, out, t);
  }
}